// Round 9
// baseline (390.414 us; speedup 1.0000x reference)
//
#include <hip/hip_runtime.h>

#define NQ 22
#define DIMN (1u << NQ)

// partials layout (floats, offset from P = ws + 2*DIMN)
// NOTE: PG/PM/PL are contiguous => 248 flat segments of 512 floats.
#define PG_OFF 0u          // genHi: 12 quantities x 512 blocks   (segs 0..11)
#define PM_OFF 6144u       // midA:  16 x 512                     (segs 12..27)
#define PL_OFF 14336u      // k_low: 110 x 1024                   (segs 28..247)
#define ACC_OFF 126976u    // measS atomic accumulators (160 floats)
#define CNT_OFF 127136u    // ticket counter (int)

// ---------------- compile-time circuit algebra (circuit is fixed) ----------------
struct MaskSet {
    unsigned L[NQ];      // CNOT-ring layer over GF(2): bit b of Lx = parity(x & L[b])
    unsigned Linv[NQ];
    unsigned xm[NQ];     // conjugated X masks
    unsigned zm[NQ];     // conjugated Z masks (suffix masks)
    unsigned frowHi[5];  // P-toggle masks for y bits 17..21 (columns of Linv)
};

constexpr MaskSet buildMasks() {
    MaskSet M{};
    for (int b = 0; b < NQ; ++b) M.L[b] = 1u << b;
    for (int q = 0; q < NQ; ++q) {
        int bc = NQ - 1 - q, bt = NQ - 1 - ((q + 1) % NQ);
        M.L[bt] ^= M.L[bc];
    }
    unsigned mat[NQ] = {}, aug[NQ] = {};
    for (int b = 0; b < NQ; ++b) { mat[b] = M.L[b]; aug[b] = 1u << b; }
    for (int col = 0; col < NQ; ++col) {
        int piv = col;
        while (!((mat[piv] >> col) & 1u)) ++piv;
        unsigned tm = mat[piv]; mat[piv] = mat[col]; mat[col] = tm;
        unsigned ta = aug[piv]; aug[piv] = aug[col]; aug[col] = ta;
        for (int r = 0; r < NQ; ++r)
            if (r != col && ((mat[r] >> col) & 1u)) { mat[r] ^= mat[col]; aug[r] ^= aug[col]; }
    }
    for (int b = 0; b < NQ; ++b) M.Linv[b] = aug[b];
    for (int j = 0; j < NQ; ++j) {
        int b = NQ - 1 - j;
        unsigned xmv = 0;
        for (int r = 0; r < NQ; ++r)
            if ((aug[r] >> b) & 1u) xmv |= 1u << r;
        M.xm[j] = xmv;       // q0..9: {21-j,20-j}; q10..20: low pairs; q21: {0,20,21}
        M.zm[j] = M.L[b];    // suffix masks
    }
    for (int j = 0; j < 5; ++j) {
        unsigned f = 0;
        for (int r = 0; r < NQ; ++r)
            if ((aug[r] >> (17 + j)) & 1u) f |= 1u << r;
        M.frowHi[j] = f;
    }
    return M;
}
constexpr int topbit_c(unsigned v) { int b = 0; while (v >> (b + 1)) ++b; return b; }
constexpr unsigned unionHi() {
    MaskSet M = buildMasks();
    unsigned u = 0;
    for (int j = 0; j < 5; ++j) u |= M.frowHi[j];
    return u;
}
static_assert((unionHi() & 0xFFFFu) == 0, "frowHi must only touch bits 16..21");

// measS slice plan: all four X masks are 2-bit-above-f4 pairs (plus optional low bit)
constexpr bool measPlanOK() {
    MaskSet M = buildMasks();
    if ((M.xm[0] & 3u) != 0u) return false;
    if ((M.xm[21] & 3u) != 1u) return false;
    if ((M.xm[4] & 3u) != 0u) return false;
    if ((M.xm[9] & 3u) != 0u) return false;
    if (topbit_c(M.xm[0] >> 2) != 19) return false;
    if (topbit_c(M.xm[21] >> 2) != 19) return false;
    if (topbit_c(M.xm[4] >> 2) != 15) return false;
    if (topbit_c(M.xm[9] >> 2) != 10) return false;
    return true;
}
static_assert(measPlanOK(), "measS slice plan must hold");

// sanity for the k_low bit plan
constexpr bool lowPlanOK() {
    MaskSet M = buildMasks();
    if ((M.xm[10] & ~0xE00u) != 0) return false;
    if ((M.xm[11] & ~0xE00u) != 0) return false;
    for (int q = 12; q <= 19; ++q) {
        if ((M.xm[q] & 3u) != 0 && (M.xm[q] & 3u) != 2u) return false;
        if ((M.zm[q] & 3u) != 0) return false;
        if (topbit_c(M.xm[q]) < 2 || topbit_c(M.xm[q]) > 9) return false;
    }
    if (M.xm[20] != 3u) return false;
    if ((M.zm[20] & 3u) != 2u) return false;
    return true;
}
static_assert(lowPlanOK(), "k_low measurement plan must hold");

__device__ __forceinline__ float fflip(float v, unsigned sbit31) {
    return __int_as_float(__float_as_int(v) ^ (int)sbit31);
}
__device__ __forceinline__ unsigned ph4(unsigned g) { return g ^ ((g >> 6) & 3u); }

// element-addressed LDS bank map for the k_low exchange phases.
__device__ __forceinline__ unsigned sA(unsigned i) {
    return i ^ ((i >> 3) & 7u) ^ (((i >> 6) & 3u) << 3);
}

// 4-quantity wave reduction: 7 shfl instead of 24.
// Returns: lane L holds the full-wave total of quantity (L&3).
__device__ __forceinline__ float fold4(float a, float b, float c, float d, int lane) {
    bool p0 = (lane & 1) != 0;
    float kL = p0 ? b : a, sL = p0 ? a : b;
    kL += __shfl_xor(sL, 1);
    float kH = p0 ? d : c, sH = p0 ? c : d;
    kH += __shfl_xor(sH, 1);
    bool p1 = (lane & 2) != 0;
    float k2 = p1 ? kH : kL, s2 = p1 ? kL : kH;
    k2 += __shfl_xor(s2, 2);
    k2 += __shfl_xor(k2, 4);
    k2 += __shfl_xor(k2, 8);
    k2 += __shfl_xor(k2, 16);
    k2 += __shfl_xor(k2, 32);
    return k2;
}

// per-block trig table build: trig[l*2NQ + b] = cos, trig[l*2NQ + NQ + b] = sin
__device__ __forceinline__ void buildTrig(float* trig, const float* __restrict__ theta, int t) {
    if (t < 2 * NQ) {
        int l = t / NQ, q = t % NQ, b = NQ - 1 - q;
        float h = 0.5f * theta[t];
        trig[l * 2 * NQ + b]      = cosf(h);
        trig[l * 2 * NQ + NQ + b] = sinf(h);
    }
}

// 3 RY gates on local element bits 0..2 (global bits b0..b0+2) for both states
__device__ __forceinline__ void gates3(float* a, float* b, const float* trig, int b0) {
#pragma unroll
    for (int g = 0; g < 3; ++g) {
        float c = trig[2 * NQ + b0 + g], s = trig[3 * NQ + b0 + g];
#pragma unroll
        for (int e = 0; e < 8; ++e) {
            if (!(e & (1 << g))) {
                int e1 = e | (1 << g);
                float x0 = a[e], x1 = a[e1];
                a[e] = c * x0 - s * x1; a[e1] = s * x0 + c * x1;
                float y0 = b[e], y1 = b[e1];
                b[e] = c * y0 - s * y1; b[e1] = s * y0 + c * y1;
            }
        }
    }
}

// segment -> accv slot mapping for the final reduce (248 segments of 512 floats)
__device__ __forceinline__ int slotOf(int s) {
    if (s < 12)  return 4 + s;                 // genHi q1..q3
    if (s < 28)  return 8 + s;                 // midA q5..q8 (20 + s-12)
    int r = (s - 28) >> 1;                     // k_low row (two halves per row)
    return (r < 44) ? (40 + r) : (88 + (r - 44));
}

// ---- generator in e=bits17..21 tile + gates 17..21 + measure q1,q2,q3 ----
__global__ __launch_bounds__(256, 1) void k_genHi(float* __restrict__ phi,
                                                  const float* __restrict__ theta,
                                                  float* __restrict__ P) {
    constexpr MaskSet M = buildMasks();
    __shared__ float red[4 * 12];
    __shared__ float trig[4 * NQ];
    // block 0: zero measS accumulators + ticket (stream-ordered before k_measS)
    if (blockIdx.x == 0) {
        if (threadIdx.x < 160) P[ACC_OFF + threadIdx.x] = 0.f;
        if (threadIdx.x == 255) *(int*)(P + CNT_OFF) = 0;
    }
    buildTrig(trig, theta, threadIdx.x);
    __syncthreads();
    unsigned base = blockIdx.x * 256u + threadIdx.x;       // y bits 0..16
    unsigned P0 = 0;
#pragma unroll
    for (int b = 0; b < NQ; ++b)
        P0 |= ((unsigned)__popc(base & M.Linv[b]) & 1u) << b;
    float pc = 1.f;
#pragma unroll
    for (int b = 1; b < 16; ++b) {
        float cvb = trig[b], svb = trig[NQ + b];
        pc *= ((P0 >> b) & 1u) ? svb : cvb;
    }
    float cv0 = trig[0], sv0 = trig[NQ];
    float C0 = pc * ((P0 & 1u) ? sv0 : cv0);
    float C1 = pc * ((P0 & 1u) ? cv0 : -sv0);
    float cb[6], sb[6];
#pragma unroll
    for (int k = 0; k < 6; ++k) { cb[k] = trig[16 + k]; sb[k] = trig[NQ + 16 + k]; }
    unsigned u0 = P0 >> 16;                                // 6 bits
    float v0[32], v1[32];
#pragma unroll
    for (int e = 0; e < 32; ++e) {
        unsigned F = 0;
        if (e & 1)  F ^= M.frowHi[0];
        if (e & 2)  F ^= M.frowHi[1];
        if (e & 4)  F ^= M.frowHi[2];
        if (e & 8)  F ^= M.frowHi[3];
        if (e & 16) F ^= M.frowHi[4];
        unsigned u = u0 ^ (F >> 16);
        float vp = (u & 1u) ? sb[0] : cb[0];
#pragma unroll
        for (int k = 1; k < 6; ++k) vp *= ((u >> k) & 1u) ? sb[k] : cb[k];
        v0[e] = vp * C0;
        v1[e] = vp * C1;
    }
    float c2[5], s2[5];
#pragma unroll
    for (int j = 0; j < 5; ++j) {
        c2[j] = trig[2 * NQ + 17 + j];
        s2[j] = trig[3 * NQ + 17 + j];
    }
#pragma unroll
    for (int j = 0; j < 5; ++j) {
#pragma unroll
        for (int e = 0; e < 32; ++e) {
            if (!(e & (1 << j))) {
                int e1 = e | (1 << j);
                float a0 = v0[e], a1 = v0[e1];
                v0[e]  = c2[j] * a0 - s2[j] * a1;
                v0[e1] = s2[j] * a0 + c2[j] * a1;
                float b0 = v1[e], b1 = v1[e1];
                v1[e]  = c2[j] * b0 - s2[j] * b1;
                v1[e1] = s2[j] * b0 + c2[j] * b1;
            }
        }
    }
#pragma unroll
    for (int e = 0; e < 32; ++e) {
        unsigned a = base | ((unsigned)e << 17);
        phi[a] = v0[e];
        phi[DIMN + a] = v1[e];
    }
    // measure q1..q3 (x-pairs and z-masks entirely within bits 17..21)
    int lane = threadIdx.x & 63, w = threadIdx.x >> 6;
#pragma unroll
    for (int i = 1; i <= 3; ++i) {
        unsigned ex  = M.xm[i] >> 17;
        unsigned zme = M.zm[i] >> 17;
        float t00 = 0.f, t11 = 0.f, t01 = 0.f, u01 = 0.f;
#pragma unroll
        for (int e = 0; e < 32; ++e) {
            int ep = e ^ (int)ex;
            t00 += v0[e] * v0[ep];
            t11 += v1[e] * v1[ep];
            float p = v0[e] * v1[ep];
            t01 += p;
            unsigned sg = ((unsigned)__popc((unsigned)ep & zme) & 1u) << 31;
            u01 += fflip(p, sg);
        }
        float r = fold4(t00, t11, t01, u01, lane);
        if (lane < 4) red[w * 12 + (i - 1) * 4 + lane] = r;
    }
    __syncthreads();
    int t = threadIdx.x;
    if (t < 12) {
        float r = red[t] + red[12 + t] + red[24 + t] + red[36 + t];
        P[PG_OFF + (unsigned)t * 512u + blockIdx.x] = r;
    }
}

// ---- e=bits12..16 tile: gates 12..16 + measure q5..q8 ----
__global__ __launch_bounds__(256, 1) void k_midA(float* __restrict__ phi,
                                                 const float* __restrict__ theta,
                                                 float* __restrict__ P) {
    constexpr MaskSet M = buildMasks();
    __shared__ float red[4 * 16];
    __shared__ float trig[4 * NQ];
    buildTrig(trig, theta, threadIdx.x);
    __syncthreads();
    unsigned tid = blockIdx.x * 256u + threadIdx.x;        // [0, 2^17)
    unsigned base = (tid & 0xFFFu) | ((tid >> 12) << 17);  // bits 0..11 + 17..21
    float v0[32], v1[32];
#pragma unroll
    for (int e = 0; e < 32; ++e) {
        unsigned a = base | ((unsigned)e << 12);
        v0[e] = phi[a];
        v1[e] = phi[DIMN + a];
    }
    float c[5], s[5];
#pragma unroll
    for (int j = 0; j < 5; ++j) {
        c[j] = trig[2 * NQ + 12 + j];
        s[j] = trig[3 * NQ + 12 + j];
    }
#pragma unroll
    for (int j = 0; j < 5; ++j) {
#pragma unroll
        for (int e = 0; e < 32; ++e) {
            if (!(e & (1 << j))) {
                int e1 = e | (1 << j);
                float a0 = v0[e], a1 = v0[e1];
                v0[e]  = c[j] * a0 - s[j] * a1;
                v0[e1] = s[j] * a0 + c[j] * a1;
                float b0 = v1[e], b1 = v1[e1];
                v1[e]  = c[j] * b0 - s[j] * b1;
                v1[e1] = s[j] * b0 + c[j] * b1;
            }
        }
    }
#pragma unroll
    for (int e = 0; e < 32; ++e) {
        unsigned a = base | ((unsigned)e << 12);
        phi[a] = v0[e];
        phi[DIMN + a] = v1[e];
    }
    // measure q5..q8 (x-pairs within bits 12..16; z-masks suffix >= 13)
    int lane = threadIdx.x & 63, w = threadIdx.x >> 6;
#pragma unroll
    for (int i = 5; i <= 8; ++i) {
        unsigned ex  = (M.xm[i] >> 12) & 31u;
        unsigned zme = (M.zm[i] >> 12) & 31u;
        unsigned bs31 = ((unsigned)__popc(base & M.zm[i]) & 1u) << 31;
        float t00 = 0.f, t11 = 0.f, t01 = 0.f, u01 = 0.f;
#pragma unroll
        for (int e = 0; e < 32; ++e) {
            int ep = e ^ (int)ex;
            t00 += v0[e] * v0[ep];
            t11 += v1[e] * v1[ep];
            float p = v0[e] * v1[ep];
            t01 += p;
            unsigned sg = ((unsigned)__popc((unsigned)ep & zme) & 1u) << 31;
            u01 += fflip(p, sg ^ bs31);
        }
        float r = fold4(t00, t11, t01, u01, lane);
        if (lane < 4) red[w * 16 + (i - 5) * 4 + lane] = r;
    }
    __syncthreads();
    int t = threadIdx.x;
    if (t < 16) {
        float r = red[t] + red[16 + t] + red[32 + t] + red[48 + t];
        P[PM_OFF + (unsigned)t * 512u + blockIdx.x] = r;
    }
}

// ---- RY layer 2 bits 0..11 + q10..q20 X/Y + ALL Z measurements ----
// 512 threads, 8 elems/thread, 4 exchange phases
__global__ __launch_bounds__(512, 4) void k_low(float* __restrict__ phi,
                                                const float* __restrict__ theta,
                                                float* __restrict__ P) {
    constexpr MaskSet M = buildMasks();
    __shared__ float As[4096];
    __shared__ float Bs[4096];
    __shared__ float redZ[8 * 33];
    __shared__ float redQ[8 * 44];
    __shared__ float trig[4 * NQ];
    float4* As4 = (float4*)As;
    float4* Bs4 = (float4*)Bs;
    int t = threadIdx.x;
    int lane = t & 63, w = t >> 6;
    unsigned base = blockIdx.x * 4096u;
    float a[8], b[8];
    buildTrig(trig, theta, t);

    // ---- P0: load (8 consecutive elems/thread), gates bits 0..2, store ----
    {
        const float4* g0 = (const float4*)(phi + base);
        const float4* g1 = (const float4*)(phi + DIMN + base);
        float4 va0 = g0[2 * t], va1 = g0[2 * t + 1];
        float4 vb0 = g1[2 * t], vb1 = g1[2 * t + 1];
        a[0] = va0.x; a[1] = va0.y; a[2] = va0.z; a[3] = va0.w;
        a[4] = va1.x; a[5] = va1.y; a[6] = va1.z; a[7] = va1.w;
        b[0] = vb0.x; b[1] = vb0.y; b[2] = vb0.z; b[3] = vb0.w;
        b[4] = vb1.x; b[5] = vb1.y; b[6] = vb1.z; b[7] = vb1.w;
        __syncthreads();               // trig ready
        gates3(a, b, trig, 0);
#pragma unroll
        for (int j = 0; j < 8; ++j) {
            unsigned i = ((unsigned)t << 3) | (unsigned)j;
            unsigned A = sA(i);
            As[A] = a[j]; Bs[A] = b[j];
        }
    }
    __syncthreads();

    // ---- X01 read (j = bits 3..5), gates 3..5, write back same addresses ----
    {
#pragma unroll
        for (int j = 0; j < 8; ++j) {
            unsigned i = (((unsigned)t >> 3) << 6) | ((unsigned)j << 3) | ((unsigned)t & 7u);
            unsigned A = sA(i);
            a[j] = As[A]; b[j] = Bs[A];
        }
        gates3(a, b, trig, 3);
#pragma unroll
        for (int j = 0; j < 8; ++j) {
            unsigned i = (((unsigned)t >> 3) << 6) | ((unsigned)j << 3) | ((unsigned)t & 7u);
            unsigned A = sA(i);
            As[A] = a[j]; Bs[A] = b[j];
        }
    }
    __syncthreads();

    // ---- X12 read (j = bits 6..8), gates 6..8, write back ----
    {
#pragma unroll
        for (int j = 0; j < 8; ++j) {
            unsigned i = (((unsigned)t >> 6) << 9) | ((unsigned)j << 6) | ((unsigned)t & 63u);
            unsigned A = sA(i);
            a[j] = As[A]; b[j] = Bs[A];
        }
        gates3(a, b, trig, 6);
#pragma unroll
        for (int j = 0; j < 8; ++j) {
            unsigned i = (((unsigned)t >> 6) << 9) | ((unsigned)j << 6) | ((unsigned)t & 63u);
            unsigned A = sA(i);
            As[A] = a[j]; Bs[A] = b[j];
        }
    }
    __syncthreads();

    // ---- X23 read (j = bits 9..11), gates 9..11 ----
    {
#pragma unroll
        for (int j = 0; j < 8; ++j) {
            unsigned i = ((unsigned)j << 9) | (unsigned)t;
            unsigned A = sA(i);
            a[j] = As[A]; b[j] = Bs[A];
        }
        gates3(a, b, trig, 9);
    }
    __syncthreads();   // protect As/Bs before measurement-layout overwrite

    // ---- write phi + measurement-layout LDS (elem i at i ^ (((i>>8)&3)<<2)) ----
#pragma unroll
    for (int j = 0; j < 8; ++j) {
        unsigned i = ((unsigned)j << 9) | (unsigned)t;
        phi[base + i] = a[j];
        phi[DIMN + base + i] = b[j];
        unsigned p = i ^ (((i >> 8) & 3u) << 2);
        As[p] = a[j]; Bs[p] = b[j];
    }

    // ---- fused Z measurement from regs: 3-level tree (bits 9..11) + lane Walsh ----
#pragma unroll
    for (int c = 0; c < 3; ++c) {
        float p[8];
#pragma unroll
        for (int j = 0; j < 8; ++j)
            p[j] = (c == 0) ? a[j] * a[j] : (c == 1) ? b[j] * b[j] : a[j] * b[j];
        float s1[4], d1[4];
#pragma unroll
        for (int j = 0; j < 4; ++j) { s1[j] = p[j] + p[j + 4]; d1[j] = p[j] - p[j + 4]; }
        float s2_0 = s1[0] + s1[2], s2_1 = s1[1] + s1[3];
        float d2_0 = d1[0] - d1[2], d2_1 = d1[1] - d1[3];
        float SS = s2_0 + s2_1;
        float z0 = (d1[0] + d1[1]) + (d1[2] + d1[3]);     // sign: bit 11
        float z1 = d2_0 + d2_1;                           // sign: bits 11,10
        float d3 = d2_0 - d2_1;                           // sign: bits 11,10,9
        float r = fold4(SS, z0, z1, 0.f, lane);
        if (lane < 3) redZ[w * 33 + c * 11 + lane] = r;
        float v = d3;
#pragma unroll
        for (int s = 0; s < 6; ++s) {
            float u = __shfl_xor(v, 1 << s);
            v = u + fflip(v, ((unsigned)(lane >> s) & 1u) << 31);
        }
        int pcnt = __popc(lane);
        if (lane == 64 - (64 >> pcnt)) redZ[w * 33 + c * 11 + 3 + pcnt] = v;
    }
    __syncthreads();   // redZ + measurement-layout As/Bs visible

    // ---- Z combine over 8 waves with wave-bit signs (elem bits 6..8) ----
    if (t < 66) {
        int c = t % 3, q = t / 3;
        int idx, wm;
        if (q == 0 || q == 21)      { idx = 9; wm = 7; }   // full suffix
        else if (q <= 9)            { idx = 0; wm = 0; }   // SS (suffix above tile)
        else if (q == 10)           { idx = 1; wm = 0; }
        else if (q == 11)           { idx = 2; wm = 0; }
        else if (q == 12)           { idx = 3; wm = 0; }
        else if (q == 13)           { idx = 3; wm = 4; }
        else if (q == 14)           { idx = 3; wm = 6; }
        else if (q == 15)           { idx = 3; wm = 7; }
        else                        { idx = q - 12; wm = 7; }  // q16..q20 -> 4..8
        float val = 0.f;
#pragma unroll
        for (int ww = 0; ww < 8; ++ww) {
            float rv = redZ[ww * 33 + c * 11 + idx];
            val += ((__popc(ww & wm) & 1) ? -rv : rv);
        }
        unsigned sg = (unsigned)__popc(base & M.zm[q]) & 1u;
        P[PL_OFF + (44u + (unsigned)t) * 1024u + blockIdx.x] = sg ? -val : val;
    }

    // ---- q10,q11 from registers (x-pairs within bits 9..11 = j bits) ----
#pragma unroll
    for (int i = 0; i < 2; ++i) {
        int q = 10 + i;
        unsigned je  = (M.xm[q] >> 9) & 7u;
        unsigned zmj = (M.zm[q] >> 9) & 7u;
        unsigned zb31 = ((unsigned)__popc(base & M.zm[q]) & 1u) << 31;
        float t00 = 0.f, t11 = 0.f, t01 = 0.f, u01 = 0.f;
#pragma unroll
        for (int j = 0; j < 8; ++j) {
            int jp = j ^ (int)je;
            t00 += a[j] * a[jp];
            t11 += b[j] * b[jp];
            float p = a[j] * b[jp];
            t01 += p;
            unsigned sg = ((unsigned)__popc((unsigned)jp & zmj) & 1u) << 31;
            u01 += fflip(p, sg ^ zb31);
        }
        float r = fold4(t00, t11, t01, u01, lane);
        if (lane < 4) redQ[w * 44 + 4 * i + lane] = r;
    }

    // ---- q12..q19 (generic float4-pair path), q20 special ----
#pragma unroll
    for (int iq = 2; iq < 10; ++iq) {
        int q = 10 + iq;
        unsigned m = M.xm[q], zm = M.zm[q];
        unsigned zb = (unsigned)__popc(base & zm) & 1u;
        int gb = topbit_c(M.xm[q]) - 2;
        unsigned mg4 = m >> 2;
        unsigned swap2 = m & 3u;            // 0 or 2
        float t00 = 0.f, t11 = 0.f, t01 = 0.f, u01 = 0.f;
        unsigned gc = (unsigned)t;          // 0..511: covers all 512 half-pairs
        unsigned g = ((gc >> gb) << (gb + 1)) | (gc & ((1u << gb) - 1u));
        unsigned gx = g ^ mg4;
        float4 a0 = As4[ph4(g)],  a1 = Bs4[ph4(g)];
        float4 b0 = As4[ph4(gx)], b1 = Bs4[ph4(gx)];
        if (swap2) {
            b0 = make_float4(b0.z, b0.w, b0.x, b0.y);
            b1 = make_float4(b1.z, b1.w, b1.x, b1.y);
        }
        unsigned szg = ((unsigned)__popc((g << 2) & zm) + zb) & 1u;
        unsigned szx = ((unsigned)__popc((gx << 2) & zm) + zb) & 1u;
        unsigned fg = szg << 31, fx = szx << 31;
        const float* A0 = &a0.x; const float* A1 = &a1.x;
        const float* B0 = &b0.x; const float* B1 = &b1.x;
#pragma unroll
        for (int j = 0; j < 4; ++j) {
            t00 += A0[j] * B0[j];
            t11 += A1[j] * B1[j];
            float p = A0[j] * B1[j], r2 = B0[j] * A1[j];
            t01 += p + r2;
            u01 += fflip(p, fx) + fflip(r2, fg);
        }
        t00 *= 2.f; t11 *= 2.f;
        float r = fold4(t00, t11, t01, u01, lane);
        if (lane < 4) redQ[w * 44 + 4 * iq + lane] = r;
    }
    {
        // q20: m = 3, partner within float4; zm&3 == 2
        unsigned zm = M.zm[20];
        unsigned zb = (unsigned)__popc(base & zm) & 1u;
        float t00 = 0.f, t11 = 0.f, t01 = 0.f, u01 = 0.f;
#pragma unroll
        for (int k = 0; k < 2; ++k) {
            unsigned g = (unsigned)t + 512u * k;
            float4 a0 = As4[ph4(g)], a1 = Bs4[ph4(g)];
            unsigned szg = ((unsigned)__popc((g << 2) & zm) + zb) & 1u;
            const float* A0 = &a0.x; const float* A1 = &a1.x;
#pragma unroll
            for (int j = 0; j < 4; ++j) {
                int jx = j ^ 3;
                float p = A0[j] * A0[jx];
                float q2 = A1[j] * A1[jx];
                float cr = A0[j] * A1[jx];
                t00 += p; t11 += q2; t01 += cr;
                unsigned sj = ((unsigned)(jx >> 1) & 1u) ^ szg;   // zm&3 == 2
                u01 += fflip(cr, sj << 31);
            }
        }
        float r = fold4(t00, t11, t01, u01, lane);
        if (lane < 4) redQ[w * 44 + 40 + lane] = r;
    }
    __syncthreads();
    if (t < 44) {
        float r = 0.f;
#pragma unroll
        for (int ww = 0; ww < 8; ++ww) r += redQ[ww * 44 + t];
        P[PL_OFF + (unsigned)t * 1024u + blockIdx.x] = r;
    }
}

// ------- X/Y slice measurements: round-0 baseline structure + ticket tail -------
// grid (512, 4): slice per blockIdx.y = q0, q4, q9, q21. atomicAdd into ACC.
__global__ __launch_bounds__(256, 8) void k_measS(const float* __restrict__ phi,
                                                  float* __restrict__ P,
                                                  float* __restrict__ out) {
    constexpr MaskSet M = buildMasks();
    __shared__ float red[16];
    __shared__ float accv[160];
    __shared__ int lastBlk;
    float* A = P + ACC_OFF;
    const float4* p0 = (const float4*)phi;
    const float4* p1 = (const float4*)(phi + DIMN);
    int t = threadIdx.x, lane = t & 63, w = t >> 6;
    constexpr int QN[4] = { 0, 4, 9, 21 };
    int qn = QN[blockIdx.y];
    unsigned m = M.xm[qn], zm = M.zm[qn];
    int gb = topbit_c(m) - 2;
    unsigned mg4 = m >> 2;
    unsigned ml2 = m & 3u;                      // 0 or 1
    unsigned zl = zm & 3u;
    unsigned pg31[4], px31[4];
#pragma unroll
    for (int j = 0; j < 4; ++j) {
        pg31[j] = (((unsigned)__popc((unsigned)j & zl) & 1u) << 31);
        px31[j] = (((unsigned)__popc(((unsigned)j ^ ml2) & zl) & 1u) << 31);
    }
    unsigned tid = blockIdx.x * 256u + (unsigned)t;   // [0, 131072)
    float t00 = 0.f, t11 = 0.f, t01 = 0.f, u01 = 0.f;
#pragma unroll
    for (int it = 0; it < 4; ++it) {
        unsigned gc = tid + (unsigned)it * 131072u;   // [0, 2^19)
        unsigned g = ((gc >> gb) << (gb + 1)) | (gc & ((1u << gb) - 1u));
        unsigned gx = g ^ mg4;
        float4 a0 = p0[g], a1 = p1[g];
        float4 b0 = p0[gx], b1 = p1[gx];
        if (ml2) {
            b0 = make_float4(b0.y, b0.x, b0.w, b0.z);
            b1 = make_float4(b1.y, b1.x, b1.w, b1.z);
        }
        unsigned fg = (((unsigned)__popc((g << 2) & zm) & 1u) << 31);
        unsigned fx = (((unsigned)__popc((gx << 2) & zm) & 1u) << 31);
        const float* A0 = &a0.x; const float* A1 = &a1.x;
        const float* B0 = &b0.x; const float* B1 = &b1.x;
#pragma unroll
        for (int j = 0; j < 4; ++j) {
            t00 += A0[j] * B0[j];
            t11 += A1[j] * B1[j];
            float p = A0[j] * B1[j], r = B0[j] * A1[j];
            t01 += p + r;
            u01 += fflip(p, fx ^ px31[j]) + fflip(r, fg ^ pg31[j]);
        }
    }
    t00 *= 2.f; t11 *= 2.f;
    {
        float r = fold4(t00, t11, t01, u01, lane);
        if (lane < 4) red[w * 4 + lane] = r;
    }
    __syncthreads();
    if (t < 4) {
        float r = red[t] + red[4 + t] + red[8 + t] + red[12 + t];
        atomicAdd(&A[4 * qn + t], r);
    }
    // ---- ticket: last of 2048 blocks reduces partials + computes the loss ----
    __threadfence();
    __syncthreads();
    if (t == 0) {
        int c = atomicAdd((int*)(P + CNT_OFF), 1);
        lastBlk = (c == 2048 - 1);
    }
    __syncthreads();
    if (!lastBlk) return;
    __threadfence();

    // init accv from atomic accumulators (holds measS results; rest zero)
    if (t < 160) accv[t] = A[t];
    __syncthreads();
    // wave-parallel coalesced reduce of 248 flat segments (512 floats each)
    {
        const float4* Pf = (const float4*)P;
        int g0w = (w < 2) ? w * 16 : 32 + (w - 2) * 15;    // groups of 4 segments
        int ng  = (w < 2) ? 16 : 15;                       // 16+16+15+15 = 62 = 248/4
        for (int gi = 0; gi < ng; ++gi) {
            int s0 = (g0w + gi) * 4;
            float q[4];
#pragma unroll
            for (int k = 0; k < 4; ++k) {
                const float4* sp = Pf + (unsigned)(s0 + k) * 128u;
                float4 x = sp[lane];
                float4 y = sp[lane + 64];
                q[k] = ((x.x + x.y) + (x.z + x.w)) + ((y.x + y.y) + (y.z + y.w));
            }
            float r = fold4(q[0], q[1], q[2], q[3], lane);
            if (lane < 4) atomicAdd(&accv[slotOf(s0 + lane)], r);
        }
    }
    __syncthreads();
    float v = 0.f;
    if (t < NQ) {
        float t00s = accv[4 * t], t11s = accv[4 * t + 1];
        float t01s = accv[4 * t + 2], u01s = accv[4 * t + 3];
        float d = t00s - t11s;
        v = 0.5f * d * d + 2.f * t01s * t01s + 2.f * u01s * u01s;   // X op + Y op
    } else if (t < 2 * NQ) {
        int q = t - NQ;
        float z0 = accv[88 + 3 * q], z1 = accv[88 + 3 * q + 1];
        float zz = accv[88 + 3 * q + 2];
        float d = z0 - z1;
        v = 0.5f * d * d + 2.f * zz * zz;                           // Z op
    }
    v += __shfl_down(v, 32); v += __shfl_down(v, 16); v += __shfl_down(v, 8);
    v += __shfl_down(v, 4);  v += __shfl_down(v, 2);  v += __shfl_down(v, 1);
    if (t == 0) out[0] = v;
}

extern "C" void kernel_launch(void* const* d_in, const int* in_sizes, int n_in,
                              void* d_out, int out_size, void* d_ws, size_t ws_size,
                              hipStream_t stream) {
    const float* theta = (const float*)d_in[0];
    float* out  = (float*)d_out;
    float* ws   = (float*)d_ws;
    float* phi  = ws;                          // 2 * DIMN floats (32 MB)
    float* P    = ws + 2 * (size_t)DIMN;       // partials + acc + ticket

    k_genHi<<<512, 256, 0, stream>>>(phi, theta, P);
    k_midA<<<512, 256, 0, stream>>>(phi, theta, P);
    k_low<<<1024, 512, 0, stream>>>(phi, theta, P);
    k_measS<<<dim3(512, 4), 256, 0, stream>>>(phi, P, out);
}

// Round 10
// 252.045 us; speedup vs baseline: 1.5490x; 1.5490x over previous
//
#include <hip/hip_runtime.h>

#define NQ 22
#define DIMN (1u << NQ)

// partials layout (floats, offset from P = ws + 2*DIMN)
// NOTE: PG/PM/PL are contiguous => 248 flat segments of 512 floats.
#define PG_OFF 0u          // genHi: 12 quantities x 512 blocks   (segs 0..11)
#define PM_OFF 6144u       // midA:  16 x 512                     (segs 12..27)
#define PL_OFF 14336u      // k_low: 110 x 1024                   (segs 28..247)
#define ACC_OFF 126976u    // measS atomic accumulators (160 floats)
#define CNT_OFF 127136u    // ticket counter (int)

// ---------------- compile-time circuit algebra (circuit is fixed) ----------------
struct MaskSet {
    unsigned L[NQ];      // CNOT-ring layer over GF(2): bit b of Lx = parity(x & L[b])
    unsigned Linv[NQ];
    unsigned xm[NQ];     // conjugated X masks
    unsigned zm[NQ];     // conjugated Z masks (suffix masks)
    unsigned frowHi[5];  // P-toggle masks for y bits 17..21 (columns of Linv)
};

constexpr MaskSet buildMasks() {
    MaskSet M{};
    for (int b = 0; b < NQ; ++b) M.L[b] = 1u << b;
    for (int q = 0; q < NQ; ++q) {
        int bc = NQ - 1 - q, bt = NQ - 1 - ((q + 1) % NQ);
        M.L[bt] ^= M.L[bc];
    }
    unsigned mat[NQ] = {}, aug[NQ] = {};
    for (int b = 0; b < NQ; ++b) { mat[b] = M.L[b]; aug[b] = 1u << b; }
    for (int col = 0; col < NQ; ++col) {
        int piv = col;
        while (!((mat[piv] >> col) & 1u)) ++piv;
        unsigned tm = mat[piv]; mat[piv] = mat[col]; mat[col] = tm;
        unsigned ta = aug[piv]; aug[piv] = aug[col]; aug[col] = ta;
        for (int r = 0; r < NQ; ++r)
            if (r != col && ((mat[r] >> col) & 1u)) { mat[r] ^= mat[col]; aug[r] ^= aug[col]; }
    }
    for (int b = 0; b < NQ; ++b) M.Linv[b] = aug[b];
    for (int j = 0; j < NQ; ++j) {
        int b = NQ - 1 - j;
        unsigned xmv = 0;
        for (int r = 0; r < NQ; ++r)
            if ((aug[r] >> b) & 1u) xmv |= 1u << r;
        M.xm[j] = xmv;       // q0..9: {21-j,20-j}; q10..20: low pairs; q21: {0,20,21}
        M.zm[j] = M.L[b];    // suffix masks
    }
    for (int j = 0; j < 5; ++j) {
        unsigned f = 0;
        for (int r = 0; r < NQ; ++r)
            if ((aug[r] >> (17 + j)) & 1u) f |= 1u << r;
        M.frowHi[j] = f;
    }
    return M;
}
constexpr int topbit_c(unsigned v) { int b = 0; while (v >> (b + 1)) ++b; return b; }
constexpr unsigned unionHi() {
    MaskSet M = buildMasks();
    unsigned u = 0;
    for (int j = 0; j < 5; ++j) u |= M.frowHi[j];
    return u;
}
static_assert((unionHi() & 0xFFFFu) == 0, "frowHi must only touch bits 16..21");

// measS slice plan: all four X masks are 2-bit-above-f4 pairs (plus optional low bit)
constexpr bool measPlanOK() {
    MaskSet M = buildMasks();
    if ((M.xm[0] & 3u) != 0u) return false;
    if ((M.xm[21] & 3u) != 1u) return false;
    if ((M.xm[4] & 3u) != 0u) return false;
    if ((M.xm[9] & 3u) != 0u) return false;
    if (topbit_c(M.xm[0] >> 2) != 19) return false;
    if (topbit_c(M.xm[21] >> 2) != 19) return false;
    if (topbit_c(M.xm[4] >> 2) != 15) return false;
    if (topbit_c(M.xm[9] >> 2) != 10) return false;
    return true;
}
static_assert(measPlanOK(), "measS slice plan must hold");

// sanity for the k_low bit plan
constexpr bool lowPlanOK() {
    MaskSet M = buildMasks();
    if ((M.xm[10] & ~0xE00u) != 0) return false;
    if ((M.xm[11] & ~0xE00u) != 0) return false;
    for (int q = 12; q <= 19; ++q) {
        if ((M.xm[q] & 3u) != 0 && (M.xm[q] & 3u) != 2u) return false;
        if ((M.zm[q] & 3u) != 0) return false;
        if (topbit_c(M.xm[q]) < 2 || topbit_c(M.xm[q]) > 9) return false;
    }
    if (M.xm[20] != 3u) return false;
    if ((M.zm[20] & 3u) != 2u) return false;
    return true;
}
static_assert(lowPlanOK(), "k_low measurement plan must hold");

__device__ __forceinline__ float fflip(float v, unsigned sbit31) {
    return __int_as_float(__float_as_int(v) ^ (int)sbit31);
}
__device__ __forceinline__ unsigned ph4(unsigned g) { return g ^ ((g >> 6) & 3u); }

// element-addressed LDS bank map for the k_low exchange phases.
__device__ __forceinline__ unsigned sA(unsigned i) {
    return i ^ ((i >> 3) & 7u) ^ (((i >> 6) & 3u) << 3);
}

// 4-quantity wave reduction: 7 shfl instead of 24.
// Returns: lane L holds the full-wave total of quantity (L&3).
__device__ __forceinline__ float fold4(float a, float b, float c, float d, int lane) {
    bool p0 = (lane & 1) != 0;
    float kL = p0 ? b : a, sL = p0 ? a : b;
    kL += __shfl_xor(sL, 1);
    float kH = p0 ? d : c, sH = p0 ? c : d;
    kH += __shfl_xor(sH, 1);
    bool p1 = (lane & 2) != 0;
    float k2 = p1 ? kH : kL, s2 = p1 ? kL : kH;
    k2 += __shfl_xor(s2, 2);
    k2 += __shfl_xor(k2, 4);
    k2 += __shfl_xor(k2, 8);
    k2 += __shfl_xor(k2, 16);
    k2 += __shfl_xor(k2, 32);
    return k2;
}

// per-block trig table build: trig[l*2NQ + b] = cos, trig[l*2NQ + NQ + b] = sin
__device__ __forceinline__ void buildTrig(float* trig, const float* __restrict__ theta, int t) {
    if (t < 2 * NQ) {
        int l = t / NQ, q = t % NQ, b = NQ - 1 - q;
        float h = 0.5f * theta[t];
        trig[l * 2 * NQ + b]      = cosf(h);
        trig[l * 2 * NQ + NQ + b] = sinf(h);
    }
}

// 3 RY gates on local element bits 0..2 (global bits b0..b0+2) for both states
__device__ __forceinline__ void gates3(float* a, float* b, const float* trig, int b0) {
#pragma unroll
    for (int g = 0; g < 3; ++g) {
        float c = trig[2 * NQ + b0 + g], s = trig[3 * NQ + b0 + g];
#pragma unroll
        for (int e = 0; e < 8; ++e) {
            if (!(e & (1 << g))) {
                int e1 = e | (1 << g);
                float x0 = a[e], x1 = a[e1];
                a[e] = c * x0 - s * x1; a[e1] = s * x0 + c * x1;
                float y0 = b[e], y1 = b[e1];
                b[e] = c * y0 - s * y1; b[e1] = s * y0 + c * y1;
            }
        }
    }
}

// segment -> accv slot mapping for the final reduce (248 segments of 512 floats)
__device__ __forceinline__ int slotOf(int s) {
    if (s < 12)  return 4 + s;                 // genHi q1..q3
    if (s < 28)  return 8 + s;                 // midA q5..q8 (20 + s-12)
    int r = (s - 28) >> 1;                     // k_low row (two halves per row)
    return (r < 44) ? (40 + r) : (88 + (r - 44));
}

// ---- generator in e=bits17..21 tile + gates 17..21 + measure q1,q2,q3 ----
__global__ __launch_bounds__(256, 1) void k_genHi(float* __restrict__ phi,
                                                  const float* __restrict__ theta,
                                                  float* __restrict__ P) {
    constexpr MaskSet M = buildMasks();
    __shared__ float red[4 * 12];
    __shared__ float trig[4 * NQ];
    // block 0: zero measS accumulators + ticket (stream-ordered before k_measS)
    if (blockIdx.x == 0) {
        if (threadIdx.x < 160) P[ACC_OFF + threadIdx.x] = 0.f;
        if (threadIdx.x == 255) *(int*)(P + CNT_OFF) = 0;
    }
    buildTrig(trig, theta, threadIdx.x);
    __syncthreads();
    unsigned base = blockIdx.x * 256u + threadIdx.x;       // y bits 0..16
    unsigned P0 = 0;
#pragma unroll
    for (int b = 0; b < NQ; ++b)
        P0 |= ((unsigned)__popc(base & M.Linv[b]) & 1u) << b;
    float pc = 1.f;
#pragma unroll
    for (int b = 1; b < 16; ++b) {
        float cvb = trig[b], svb = trig[NQ + b];
        pc *= ((P0 >> b) & 1u) ? svb : cvb;
    }
    float cv0 = trig[0], sv0 = trig[NQ];
    float C0 = pc * ((P0 & 1u) ? sv0 : cv0);
    float C1 = pc * ((P0 & 1u) ? cv0 : -sv0);
    float cb[6], sb[6];
#pragma unroll
    for (int k = 0; k < 6; ++k) { cb[k] = trig[16 + k]; sb[k] = trig[NQ + 16 + k]; }
    unsigned u0 = P0 >> 16;                                // 6 bits
    float v0[32], v1[32];
#pragma unroll
    for (int e = 0; e < 32; ++e) {
        unsigned F = 0;
        if (e & 1)  F ^= M.frowHi[0];
        if (e & 2)  F ^= M.frowHi[1];
        if (e & 4)  F ^= M.frowHi[2];
        if (e & 8)  F ^= M.frowHi[3];
        if (e & 16) F ^= M.frowHi[4];
        unsigned u = u0 ^ (F >> 16);
        float vp = (u & 1u) ? sb[0] : cb[0];
#pragma unroll
        for (int k = 1; k < 6; ++k) vp *= ((u >> k) & 1u) ? sb[k] : cb[k];
        v0[e] = vp * C0;
        v1[e] = vp * C1;
    }
    float c2[5], s2[5];
#pragma unroll
    for (int j = 0; j < 5; ++j) {
        c2[j] = trig[2 * NQ + 17 + j];
        s2[j] = trig[3 * NQ + 17 + j];
    }
#pragma unroll
    for (int j = 0; j < 5; ++j) {
#pragma unroll
        for (int e = 0; e < 32; ++e) {
            if (!(e & (1 << j))) {
                int e1 = e | (1 << j);
                float a0 = v0[e], a1 = v0[e1];
                v0[e]  = c2[j] * a0 - s2[j] * a1;
                v0[e1] = s2[j] * a0 + c2[j] * a1;
                float b0 = v1[e], b1 = v1[e1];
                v1[e]  = c2[j] * b0 - s2[j] * b1;
                v1[e1] = s2[j] * b0 + c2[j] * b1;
            }
        }
    }
#pragma unroll
    for (int e = 0; e < 32; ++e) {
        unsigned a = base | ((unsigned)e << 17);
        phi[a] = v0[e];
        phi[DIMN + a] = v1[e];
    }
    // measure q1..q3 (x-pairs and z-masks entirely within bits 17..21)
    int lane = threadIdx.x & 63, w = threadIdx.x >> 6;
#pragma unroll
    for (int i = 1; i <= 3; ++i) {
        unsigned ex  = M.xm[i] >> 17;
        unsigned zme = M.zm[i] >> 17;
        float t00 = 0.f, t11 = 0.f, t01 = 0.f, u01 = 0.f;
#pragma unroll
        for (int e = 0; e < 32; ++e) {
            int ep = e ^ (int)ex;
            t00 += v0[e] * v0[ep];
            t11 += v1[e] * v1[ep];
            float p = v0[e] * v1[ep];
            t01 += p;
            unsigned sg = ((unsigned)__popc((unsigned)ep & zme) & 1u) << 31;
            u01 += fflip(p, sg);
        }
        float r = fold4(t00, t11, t01, u01, lane);
        if (lane < 4) red[w * 12 + (i - 1) * 4 + lane] = r;
    }
    __syncthreads();
    int t = threadIdx.x;
    if (t < 12) {
        float r = red[t] + red[12 + t] + red[24 + t] + red[36 + t];
        P[PG_OFF + (unsigned)t * 512u + blockIdx.x] = r;
    }
}

// ---- e=bits12..16 tile: gates 12..16 + measure q5..q8 ----
__global__ __launch_bounds__(256, 1) void k_midA(float* __restrict__ phi,
                                                 const float* __restrict__ theta,
                                                 float* __restrict__ P) {
    constexpr MaskSet M = buildMasks();
    __shared__ float red[4 * 16];
    __shared__ float trig[4 * NQ];
    buildTrig(trig, theta, threadIdx.x);
    __syncthreads();
    unsigned tid = blockIdx.x * 256u + threadIdx.x;        // [0, 2^17)
    unsigned base = (tid & 0xFFFu) | ((tid >> 12) << 17);  // bits 0..11 + 17..21
    float v0[32], v1[32];
#pragma unroll
    for (int e = 0; e < 32; ++e) {
        unsigned a = base | ((unsigned)e << 12);
        v0[e] = phi[a];
        v1[e] = phi[DIMN + a];
    }
    float c[5], s[5];
#pragma unroll
    for (int j = 0; j < 5; ++j) {
        c[j] = trig[2 * NQ + 12 + j];
        s[j] = trig[3 * NQ + 12 + j];
    }
#pragma unroll
    for (int j = 0; j < 5; ++j) {
#pragma unroll
        for (int e = 0; e < 32; ++e) {
            if (!(e & (1 << j))) {
                int e1 = e | (1 << j);
                float a0 = v0[e], a1 = v0[e1];
                v0[e]  = c[j] * a0 - s[j] * a1;
                v0[e1] = s[j] * a0 + c[j] * a1;
                float b0 = v1[e], b1 = v1[e1];
                v1[e]  = c[j] * b0 - s[j] * b1;
                v1[e1] = s[j] * b0 + c[j] * b1;
            }
        }
    }
#pragma unroll
    for (int e = 0; e < 32; ++e) {
        unsigned a = base | ((unsigned)e << 12);
        phi[a] = v0[e];
        phi[DIMN + a] = v1[e];
    }
    // measure q5..q8 (x-pairs within bits 12..16; z-masks suffix >= 13)
    int lane = threadIdx.x & 63, w = threadIdx.x >> 6;
#pragma unroll
    for (int i = 5; i <= 8; ++i) {
        unsigned ex  = (M.xm[i] >> 12) & 31u;
        unsigned zme = (M.zm[i] >> 12) & 31u;
        unsigned bs31 = ((unsigned)__popc(base & M.zm[i]) & 1u) << 31;
        float t00 = 0.f, t11 = 0.f, t01 = 0.f, u01 = 0.f;
#pragma unroll
        for (int e = 0; e < 32; ++e) {
            int ep = e ^ (int)ex;
            t00 += v0[e] * v0[ep];
            t11 += v1[e] * v1[ep];
            float p = v0[e] * v1[ep];
            t01 += p;
            unsigned sg = ((unsigned)__popc((unsigned)ep & zme) & 1u) << 31;
            u01 += fflip(p, sg ^ bs31);
        }
        float r = fold4(t00, t11, t01, u01, lane);
        if (lane < 4) red[w * 16 + (i - 5) * 4 + lane] = r;
    }
    __syncthreads();
    int t = threadIdx.x;
    if (t < 16) {
        float r = red[t] + red[16 + t] + red[32 + t] + red[48 + t];
        P[PM_OFF + (unsigned)t * 512u + blockIdx.x] = r;
    }
}

// ---- RY layer 2 bits 0..11 + q10..q20 X/Y + ALL Z measurements ----
// 512 threads, 8 elems/thread, 4 exchange phases
__global__ __launch_bounds__(512, 4) void k_low(float* __restrict__ phi,
                                                const float* __restrict__ theta,
                                                float* __restrict__ P) {
    constexpr MaskSet M = buildMasks();
    __shared__ float As[4096];
    __shared__ float Bs[4096];
    __shared__ float redZ[8 * 33];
    __shared__ float redQ[8 * 44];
    __shared__ float trig[4 * NQ];
    float4* As4 = (float4*)As;
    float4* Bs4 = (float4*)Bs;
    int t = threadIdx.x;
    int lane = t & 63, w = t >> 6;
    unsigned base = blockIdx.x * 4096u;
    float a[8], b[8];
    buildTrig(trig, theta, t);

    // ---- P0: load (8 consecutive elems/thread), gates bits 0..2, store ----
    {
        const float4* g0 = (const float4*)(phi + base);
        const float4* g1 = (const float4*)(phi + DIMN + base);
        float4 va0 = g0[2 * t], va1 = g0[2 * t + 1];
        float4 vb0 = g1[2 * t], vb1 = g1[2 * t + 1];
        a[0] = va0.x; a[1] = va0.y; a[2] = va0.z; a[3] = va0.w;
        a[4] = va1.x; a[5] = va1.y; a[6] = va1.z; a[7] = va1.w;
        b[0] = vb0.x; b[1] = vb0.y; b[2] = vb0.z; b[3] = vb0.w;
        b[4] = vb1.x; b[5] = vb1.y; b[6] = vb1.z; b[7] = vb1.w;
        __syncthreads();               // trig ready
        gates3(a, b, trig, 0);
#pragma unroll
        for (int j = 0; j < 8; ++j) {
            unsigned i = ((unsigned)t << 3) | (unsigned)j;
            unsigned A = sA(i);
            As[A] = a[j]; Bs[A] = b[j];
        }
    }
    __syncthreads();

    // ---- X01 read (j = bits 3..5), gates 3..5, write back same addresses ----
    {
#pragma unroll
        for (int j = 0; j < 8; ++j) {
            unsigned i = (((unsigned)t >> 3) << 6) | ((unsigned)j << 3) | ((unsigned)t & 7u);
            unsigned A = sA(i);
            a[j] = As[A]; b[j] = Bs[A];
        }
        gates3(a, b, trig, 3);
#pragma unroll
        for (int j = 0; j < 8; ++j) {
            unsigned i = (((unsigned)t >> 3) << 6) | ((unsigned)j << 3) | ((unsigned)t & 7u);
            unsigned A = sA(i);
            As[A] = a[j]; Bs[A] = b[j];
        }
    }
    __syncthreads();

    // ---- X12 read (j = bits 6..8), gates 6..8, write back ----
    {
#pragma unroll
        for (int j = 0; j < 8; ++j) {
            unsigned i = (((unsigned)t >> 6) << 9) | ((unsigned)j << 6) | ((unsigned)t & 63u);
            unsigned A = sA(i);
            a[j] = As[A]; b[j] = Bs[A];
        }
        gates3(a, b, trig, 6);
#pragma unroll
        for (int j = 0; j < 8; ++j) {
            unsigned i = (((unsigned)t >> 6) << 9) | ((unsigned)j << 6) | ((unsigned)t & 63u);
            unsigned A = sA(i);
            As[A] = a[j]; Bs[A] = b[j];
        }
    }
    __syncthreads();

    // ---- X23 read (j = bits 9..11), gates 9..11 ----
    {
#pragma unroll
        for (int j = 0; j < 8; ++j) {
            unsigned i = ((unsigned)j << 9) | (unsigned)t;
            unsigned A = sA(i);
            a[j] = As[A]; b[j] = Bs[A];
        }
        gates3(a, b, trig, 9);
    }
    __syncthreads();   // protect As/Bs before measurement-layout overwrite

    // ---- write phi + measurement-layout LDS (elem i at i ^ (((i>>8)&3)<<2)) ----
#pragma unroll
    for (int j = 0; j < 8; ++j) {
        unsigned i = ((unsigned)j << 9) | (unsigned)t;
        phi[base + i] = a[j];
        phi[DIMN + base + i] = b[j];
        unsigned p = i ^ (((i >> 8) & 3u) << 2);
        As[p] = a[j]; Bs[p] = b[j];
    }

    // ---- fused Z measurement from regs: 3-level tree (bits 9..11) + lane Walsh ----
#pragma unroll
    for (int c = 0; c < 3; ++c) {
        float p[8];
#pragma unroll
        for (int j = 0; j < 8; ++j)
            p[j] = (c == 0) ? a[j] * a[j] : (c == 1) ? b[j] * b[j] : a[j] * b[j];
        float s1[4], d1[4];
#pragma unroll
        for (int j = 0; j < 4; ++j) { s1[j] = p[j] + p[j + 4]; d1[j] = p[j] - p[j + 4]; }
        float s2_0 = s1[0] + s1[2], s2_1 = s1[1] + s1[3];
        float d2_0 = d1[0] - d1[2], d2_1 = d1[1] - d1[3];
        float SS = s2_0 + s2_1;
        float z0 = (d1[0] + d1[1]) + (d1[2] + d1[3]);     // sign: bit 11
        float z1 = d2_0 + d2_1;                           // sign: bits 11,10
        float d3 = d2_0 - d2_1;                           // sign: bits 11,10,9
        float r = fold4(SS, z0, z1, 0.f, lane);
        if (lane < 3) redZ[w * 33 + c * 11 + lane] = r;
        float v = d3;
#pragma unroll
        for (int s = 0; s < 6; ++s) {
            float u = __shfl_xor(v, 1 << s);
            v = u + fflip(v, ((unsigned)(lane >> s) & 1u) << 31);
        }
        int pcnt = __popc(lane);
        if (lane == 64 - (64 >> pcnt)) redZ[w * 33 + c * 11 + 3 + pcnt] = v;
    }
    __syncthreads();   // redZ + measurement-layout As/Bs visible

    // ---- Z combine over 8 waves with wave-bit signs (elem bits 6..8) ----
    if (t < 66) {
        int c = t % 3, q = t / 3;
        int idx, wm;
        if (q == 0 || q == 21)      { idx = 9; wm = 7; }   // full suffix
        else if (q <= 9)            { idx = 0; wm = 0; }   // SS (suffix above tile)
        else if (q == 10)           { idx = 1; wm = 0; }
        else if (q == 11)           { idx = 2; wm = 0; }
        else if (q == 12)           { idx = 3; wm = 0; }
        else if (q == 13)           { idx = 3; wm = 4; }
        else if (q == 14)           { idx = 3; wm = 6; }
        else if (q == 15)           { idx = 3; wm = 7; }
        else                        { idx = q - 12; wm = 7; }  // q16..q20 -> 4..8
        float val = 0.f;
#pragma unroll
        for (int ww = 0; ww < 8; ++ww) {
            float rv = redZ[ww * 33 + c * 11 + idx];
            val += ((__popc(ww & wm) & 1) ? -rv : rv);
        }
        unsigned sg = (unsigned)__popc(base & M.zm[q]) & 1u;
        P[PL_OFF + (44u + (unsigned)t) * 1024u + blockIdx.x] = sg ? -val : val;
    }

    // ---- q10,q11 from registers (x-pairs within bits 9..11 = j bits) ----
#pragma unroll
    for (int i = 0; i < 2; ++i) {
        int q = 10 + i;
        unsigned je  = (M.xm[q] >> 9) & 7u;
        unsigned zmj = (M.zm[q] >> 9) & 7u;
        unsigned zb31 = ((unsigned)__popc(base & M.zm[q]) & 1u) << 31;
        float t00 = 0.f, t11 = 0.f, t01 = 0.f, u01 = 0.f;
#pragma unroll
        for (int j = 0; j < 8; ++j) {
            int jp = j ^ (int)je;
            t00 += a[j] * a[jp];
            t11 += b[j] * b[jp];
            float p = a[j] * b[jp];
            t01 += p;
            unsigned sg = ((unsigned)__popc((unsigned)jp & zmj) & 1u) << 31;
            u01 += fflip(p, sg ^ zb31);
        }
        float r = fold4(t00, t11, t01, u01, lane);
        if (lane < 4) redQ[w * 44 + 4 * i + lane] = r;
    }

    // ---- q12..q19 (generic float4-pair path), q20 special ----
#pragma unroll
    for (int iq = 2; iq < 10; ++iq) {
        int q = 10 + iq;
        unsigned m = M.xm[q], zm = M.zm[q];
        unsigned zb = (unsigned)__popc(base & zm) & 1u;
        int gb = topbit_c(M.xm[q]) - 2;
        unsigned mg4 = m >> 2;
        unsigned swap2 = m & 3u;            // 0 or 2
        float t00 = 0.f, t11 = 0.f, t01 = 0.f, u01 = 0.f;
        unsigned gc = (unsigned)t;          // 0..511: covers all 512 half-pairs
        unsigned g = ((gc >> gb) << (gb + 1)) | (gc & ((1u << gb) - 1u));
        unsigned gx = g ^ mg4;
        float4 a0 = As4[ph4(g)],  a1 = Bs4[ph4(g)];
        float4 b0 = As4[ph4(gx)], b1 = Bs4[ph4(gx)];
        if (swap2) {
            b0 = make_float4(b0.z, b0.w, b0.x, b0.y);
            b1 = make_float4(b1.z, b1.w, b1.x, b1.y);
        }
        unsigned szg = ((unsigned)__popc((g << 2) & zm) + zb) & 1u;
        unsigned szx = ((unsigned)__popc((gx << 2) & zm) + zb) & 1u;
        unsigned fg = szg << 31, fx = szx << 31;
        const float* A0 = &a0.x; const float* A1 = &a1.x;
        const float* B0 = &b0.x; const float* B1 = &b1.x;
#pragma unroll
        for (int j = 0; j < 4; ++j) {
            t00 += A0[j] * B0[j];
            t11 += A1[j] * B1[j];
            float p = A0[j] * B1[j], r2 = B0[j] * A1[j];
            t01 += p + r2;
            u01 += fflip(p, fx) + fflip(r2, fg);
        }
        t00 *= 2.f; t11 *= 2.f;
        float r = fold4(t00, t11, t01, u01, lane);
        if (lane < 4) redQ[w * 44 + 4 * iq + lane] = r;
    }
    {
        // q20: m = 3, partner within float4; zm&3 == 2
        unsigned zm = M.zm[20];
        unsigned zb = (unsigned)__popc(base & zm) & 1u;
        float t00 = 0.f, t11 = 0.f, t01 = 0.f, u01 = 0.f;
#pragma unroll
        for (int k = 0; k < 2; ++k) {
            unsigned g = (unsigned)t + 512u * k;
            float4 a0 = As4[ph4(g)], a1 = Bs4[ph4(g)];
            unsigned szg = ((unsigned)__popc((g << 2) & zm) + zb) & 1u;
            const float* A0 = &a0.x; const float* A1 = &a1.x;
#pragma unroll
            for (int j = 0; j < 4; ++j) {
                int jx = j ^ 3;
                float p = A0[j] * A0[jx];
                float q2 = A1[j] * A1[jx];
                float cr = A0[j] * A1[jx];
                t00 += p; t11 += q2; t01 += cr;
                unsigned sj = ((unsigned)(jx >> 1) & 1u) ^ szg;   // zm&3 == 2
                u01 += fflip(cr, sj << 31);
            }
        }
        float r = fold4(t00, t11, t01, u01, lane);
        if (lane < 4) redQ[w * 44 + 40 + lane] = r;
    }
    __syncthreads();
    if (t < 44) {
        float r = 0.f;
#pragma unroll
        for (int ww = 0; ww < 8; ++ww) r += redQ[ww * 44 + t];
        P[PL_OFF + (unsigned)t * 1024u + blockIdx.x] = r;
    }
}

// ------- X/Y slice measurements: EXACT round-0 launch config + ticket tail -------
// grid (256, 4): slice per blockIdx.y = q0, q4, q9, q21; 8 unrolled iters/thread.
// No VGPR constraint: let the compiler pipeline 32 loads in flight (round-0 proven).
__global__ __launch_bounds__(256) void k_measS(const float* __restrict__ phi,
                                               float* __restrict__ P,
                                               float* __restrict__ out) {
    constexpr MaskSet M = buildMasks();
    __shared__ float red[16];
    __shared__ float accv[160];
    __shared__ int lastBlk;
    float* A = P + ACC_OFF;
    const float4* p0 = (const float4*)phi;
    const float4* p1 = (const float4*)(phi + DIMN);
    int t = threadIdx.x, lane = t & 63, w = t >> 6;
    constexpr int QN[4] = { 0, 4, 9, 21 };
    int qn = QN[blockIdx.y];
    unsigned m = M.xm[qn], zm = M.zm[qn];
    int gb = topbit_c(m) - 2;
    unsigned mg4 = m >> 2;
    unsigned ml2 = m & 3u;                      // 0 or 1
    unsigned zl = zm & 3u;
    unsigned pg31[4], px31[4];
#pragma unroll
    for (int j = 0; j < 4; ++j) {
        pg31[j] = (((unsigned)__popc((unsigned)j & zl) & 1u) << 31);
        px31[j] = (((unsigned)__popc(((unsigned)j ^ ml2) & zl) & 1u) << 31);
    }
    unsigned tid = blockIdx.x * 256u + (unsigned)t;   // [0, 65536)
    float t00 = 0.f, t11 = 0.f, t01 = 0.f, u01 = 0.f;
#pragma unroll
    for (int it = 0; it < 8; ++it) {
        unsigned gc = tid + (unsigned)it * 65536u;    // [0, 2^19)
        unsigned g = ((gc >> gb) << (gb + 1)) | (gc & ((1u << gb) - 1u));
        unsigned gx = g ^ mg4;
        float4 a0 = p0[g], a1 = p1[g];
        float4 b0 = p0[gx], b1 = p1[gx];
        if (ml2) {
            b0 = make_float4(b0.y, b0.x, b0.w, b0.z);
            b1 = make_float4(b1.y, b1.x, b1.w, b1.z);
        }
        unsigned fg = (((unsigned)__popc((g << 2) & zm) & 1u) << 31);
        unsigned fx = (((unsigned)__popc((gx << 2) & zm) & 1u) << 31);
        const float* A0 = &a0.x; const float* A1 = &a1.x;
        const float* B0 = &b0.x; const float* B1 = &b1.x;
#pragma unroll
        for (int j = 0; j < 4; ++j) {
            t00 += A0[j] * B0[j];
            t11 += A1[j] * B1[j];
            float p = A0[j] * B1[j], r = B0[j] * A1[j];
            t01 += p + r;
            u01 += fflip(p, fx ^ px31[j]) + fflip(r, fg ^ pg31[j]);
        }
    }
    t00 *= 2.f; t11 *= 2.f;
    {
        float r = fold4(t00, t11, t01, u01, lane);
        if (lane < 4) red[w * 4 + lane] = r;
    }
    __syncthreads();
    if (t < 4) {
        float r = red[t] + red[4 + t] + red[8 + t] + red[12 + t];
        atomicAdd(&A[4 * qn + t], r);
    }
    // ---- ticket: last of 1024 blocks reduces partials + computes the loss ----
    __threadfence();
    __syncthreads();
    if (t == 0) {
        int c = atomicAdd((int*)(P + CNT_OFF), 1);
        lastBlk = (c == 1024 - 1);
    }
    __syncthreads();
    if (!lastBlk) return;
    __threadfence();

    // init accv from atomic accumulators (holds measS results; rest zero)
    if (t < 160) accv[t] = A[t];
    __syncthreads();
    // wave-parallel coalesced reduce of 248 flat segments (512 floats each)
    {
        const float4* Pf = (const float4*)P;
        int g0w = (w < 2) ? w * 16 : 32 + (w - 2) * 15;    // groups of 4 segments
        int ng  = (w < 2) ? 16 : 15;                       // 16+16+15+15 = 62 = 248/4
        for (int gi = 0; gi < ng; ++gi) {
            int s0 = (g0w + gi) * 4;
            float q[4];
#pragma unroll
            for (int k = 0; k < 4; ++k) {
                const float4* sp = Pf + (unsigned)(s0 + k) * 128u;
                float4 x = sp[lane];
                float4 y = sp[lane + 64];
                q[k] = ((x.x + x.y) + (x.z + x.w)) + ((y.x + y.y) + (y.z + y.w));
            }
            float r = fold4(q[0], q[1], q[2], q[3], lane);
            if (lane < 4) atomicAdd(&accv[slotOf(s0 + lane)], r);
        }
    }
    __syncthreads();
    float v = 0.f;
    if (t < NQ) {
        float t00s = accv[4 * t], t11s = accv[4 * t + 1];
        float t01s = accv[4 * t + 2], u01s = accv[4 * t + 3];
        float d = t00s - t11s;
        v = 0.5f * d * d + 2.f * t01s * t01s + 2.f * u01s * u01s;   // X op + Y op
    } else if (t < 2 * NQ) {
        int q = t - NQ;
        float z0 = accv[88 + 3 * q], z1 = accv[88 + 3 * q + 1];
        float zz = accv[88 + 3 * q + 2];
        float d = z0 - z1;
        v = 0.5f * d * d + 2.f * zz * zz;                           // Z op
    }
    v += __shfl_down(v, 32); v += __shfl_down(v, 16); v += __shfl_down(v, 8);
    v += __shfl_down(v, 4);  v += __shfl_down(v, 2);  v += __shfl_down(v, 1);
    if (t == 0) out[0] = v;
}

extern "C" void kernel_launch(void* const* d_in, const int* in_sizes, int n_in,
                              void* d_out, int out_size, void* d_ws, size_t ws_size,
                              hipStream_t stream) {
    const float* theta = (const float*)d_in[0];
    float* out  = (float*)d_out;
    float* ws   = (float*)d_ws;
    float* phi  = ws;                          // 2 * DIMN floats (32 MB)
    float* P    = ws + 2 * (size_t)DIMN;       // partials + acc + ticket

    k_genHi<<<512, 256, 0, stream>>>(phi, theta, P);
    k_midA<<<512, 256, 0, stream>>>(phi, theta, P);
    k_low<<<1024, 512, 0, stream>>>(phi, theta, P);
    k_measS<<<dim3(256, 4), 256, 0, stream>>>(phi, P, out);
}

// Round 11
// 156.224 us; speedup vs baseline: 2.4991x; 1.6134x over previous
//
#include <hip/hip_runtime.h>

#define NQ 22
#define DIMN (1u << NQ)

// ---------------- compile-time circuit algebra (circuit is fixed) ----------------
struct MaskSet {
    unsigned L[NQ];      // CNOT-ring layer over GF(2): bit b of Lx = parity(x & L[b])
    unsigned Linv[NQ];
    unsigned xm[NQ];     // conjugated X masks
    unsigned zm[NQ];     // conjugated Z masks (suffix masks)
    unsigned frowHi[5];  // P-toggle masks for y bits 17..21 (columns of Linv)
};

constexpr MaskSet buildMasks() {
    MaskSet M{};
    for (int b = 0; b < NQ; ++b) M.L[b] = 1u << b;
    for (int q = 0; q < NQ; ++q) {
        int bc = NQ - 1 - q, bt = NQ - 1 - ((q + 1) % NQ);
        M.L[bt] ^= M.L[bc];
    }
    unsigned mat[NQ] = {}, aug[NQ] = {};
    for (int b = 0; b < NQ; ++b) { mat[b] = M.L[b]; aug[b] = 1u << b; }
    for (int col = 0; col < NQ; ++col) {
        int piv = col;
        while (!((mat[piv] >> col) & 1u)) ++piv;
        unsigned tm = mat[piv]; mat[piv] = mat[col]; mat[col] = tm;
        unsigned ta = aug[piv]; aug[piv] = aug[col]; aug[col] = ta;
        for (int r = 0; r < NQ; ++r)
            if (r != col && ((mat[r] >> col) & 1u)) { mat[r] ^= mat[col]; aug[r] ^= aug[col]; }
    }
    for (int b = 0; b < NQ; ++b) M.Linv[b] = aug[b];
    for (int j = 0; j < NQ; ++j) {
        int b = NQ - 1 - j;
        unsigned xmv = 0;
        for (int r = 0; r < NQ; ++r)
            if ((aug[r] >> b) & 1u) xmv |= 1u << r;
        M.xm[j] = xmv;       // q0..9: {21-j,20-j}; q10..20: low pairs; q21: {0,20,21}
        M.zm[j] = M.L[b];    // suffix masks
    }
    for (int j = 0; j < 5; ++j) {
        unsigned f = 0;
        for (int r = 0; r < NQ; ++r)
            if ((aug[r] >> (17 + j)) & 1u) f |= 1u << r;
        M.frowHi[j] = f;
    }
    return M;
}
constexpr int topbit_c(unsigned v) { int b = 0; while (v >> (b + 1)) ++b; return b; }
constexpr unsigned unionHi() {
    MaskSet M = buildMasks();
    unsigned u = 0;
    for (int j = 0; j < 5; ++j) u |= M.frowHi[j];
    return u;
}
static_assert((unionHi() & 0xFFFFu) == 0, "frowHi must only touch bits 16..21");

// ---- orbit structure for the fused slice-measurement kernel (q0,q4,q9,q21) ----
constexpr unsigned orbGen(int which) {
    MaskSet M = buildMasks();
    return (which == 0 ? M.xm[0] : which == 1 ? M.xm[4] : M.xm[9]) >> 2;
}
constexpr int orbS21() {
    MaskSet M = buildMasks();
    unsigned GA = M.xm[0] >> 2, GB = M.xm[4] >> 2, GC = M.xm[9] >> 2;
    unsigned GQ = M.xm[21] >> 2;
    for (int s = 1; s < 8; ++s) {
        unsigned c = ((s & 1) ? GA : 0u) ^ ((s & 2) ? GB : 0u) ^ ((s & 4) ? GC : 0u);
        if (c == GQ) return s;
    }
    return -1;
}
constexpr bool orbitOK() {
    unsigned GA = orbGen(0), GB = orbGen(1), GC = orbGen(2);
    int cA = topbit_c(GA), cB = topbit_c(GB), cC = topbit_c(GC);
    if (!(cC < cB && cB < cA) || cA > 19) return false;
    if (((GA >> cB) & 1u) || ((GA >> cC) & 1u)) return false;
    if (((GB >> cA) & 1u) || ((GB >> cC) & 1u)) return false;
    if (((GC >> cA) & 1u) || ((GC >> cB) & 1u)) return false;
    return orbS21() > 0;
}
static_assert(orbitOK(), "orbit structure for fused slice measurement must hold");

// sanity for the k_low bit plan: q10,q11 X-pairs inside bits 9..11; q12..q19
// generic (m&3==0, zm&3==0); q20 special (m==3, zm&3==2)
constexpr bool lowPlanOK() {
    MaskSet M = buildMasks();
    if ((M.xm[10] & ~0xE00u) != 0) return false;
    if ((M.xm[11] & ~0xE00u) != 0) return false;
    for (int q = 12; q <= 19; ++q) {
        if ((M.xm[q] & 3u) != 0 && (M.xm[q] & 3u) != 2u) return false;
        if ((M.zm[q] & 3u) != 0) return false;
        if (topbit_c(M.xm[q]) < 2 || topbit_c(M.xm[q]) > 9) return false;
    }
    if (M.xm[20] != 3u) return false;
    if ((M.zm[20] & 3u) != 2u) return false;
    return true;
}
static_assert(lowPlanOK(), "k_low measurement plan must hold");

__device__ __forceinline__ float fflip(float v, unsigned sbit31) {
    return __int_as_float(__float_as_int(v) ^ (int)sbit31);
}
__device__ __forceinline__ unsigned ph4(unsigned g) { return g ^ ((g >> 6) & 3u); }

// element-addressed LDS bank map for the k_low exchange phases.
// A(i) = i ^ ((i>>3)&7) ^ (((i>>6)&3)<<3): bank bits = (i0^i3, i1^i4, i2^i5, i3^i6, i4^i7)
// -> full-rank on every phase's lane-entropy subspace => <=2 lanes/bank (free).
__device__ __forceinline__ unsigned sA(unsigned i) {
    return i ^ ((i >> 3) & 7u) ^ (((i >> 6) & 3u) << 3);
}

// 4-quantity wave reduction: 7 shfl instead of 24.
// Returns: lane L holds the full-wave total of quantity (L&3).
__device__ __forceinline__ float fold4(float a, float b, float c, float d, int lane) {
    bool p0 = (lane & 1) != 0;
    float kL = p0 ? b : a, sL = p0 ? a : b;
    kL += __shfl_xor(sL, 1);
    float kH = p0 ? d : c, sH = p0 ? c : d;
    kH += __shfl_xor(sH, 1);
    bool p1 = (lane & 2) != 0;
    float k2 = p1 ? kH : kL, s2 = p1 ? kL : kH;
    k2 += __shfl_xor(s2, 2);
    k2 += __shfl_xor(k2, 4);
    k2 += __shfl_xor(k2, 8);
    k2 += __shfl_xor(k2, 16);
    k2 += __shfl_xor(k2, 32);
    return k2;
}

// 3 RY gates on local element bits 0..2 (global bits b0..b0+2) for both states
__device__ __forceinline__ void gates3(float* a, float* b, const float* __restrict__ trig, int b0) {
#pragma unroll
    for (int g = 0; g < 3; ++g) {
        float c = trig[2 * NQ + b0 + g], s = trig[3 * NQ + b0 + g];
#pragma unroll
        for (int e = 0; e < 8; ++e) {
            if (!(e & (1 << g))) {
                int e1 = e | (1 << g);
                float x0 = a[e], x1 = a[e1];
                a[e] = c * x0 - s * x1; a[e1] = s * x0 + c * x1;
                float y0 = b[e], y1 = b[e1];
                b[e] = c * y0 - s * y1; b[e1] = s * y0 + c * y1;
            }
        }
    }
}

// ---------------- prep: zero accumulators, compute cos/sin tables ----------------
__global__ __launch_bounds__(256) void k_prep(const float* __restrict__ theta,
                                              float* __restrict__ acc,
                                              float* __restrict__ trig) {
    int t = threadIdx.x;
    acc[t] = 0.f;
    if (t < 2 * NQ) {
        int l = t / NQ, q = t % NQ, b = NQ - 1 - q;
        float h = 0.5f * theta[t];
        trig[l * 2 * NQ + b]      = cosf(h);
        trig[l * 2 * NQ + NQ + b] = sinf(h);
    }
}

// ---- generator in e=bits17..21 tile + gates 17..21 + measure q1,q2,q3 ----
__global__ __launch_bounds__(256, 1) void k_genHi(float* __restrict__ phi,
                                                  const float* __restrict__ trig,
                                                  float* __restrict__ acc) {
    constexpr MaskSet M = buildMasks();
    __shared__ float red[4 * 12];
    unsigned base = blockIdx.x * 256u + threadIdx.x;       // y bits 0..16
    unsigned P0 = 0;
#pragma unroll
    for (int b = 0; b < NQ; ++b)
        P0 |= ((unsigned)__popc(base & M.Linv[b]) & 1u) << b;
    float pc = 1.f;
#pragma unroll
    for (int b = 1; b < 16; ++b) {
        float cvb = trig[b], svb = trig[NQ + b];
        pc *= ((P0 >> b) & 1u) ? svb : cvb;
    }
    float cv0 = trig[0], sv0 = trig[NQ];
    float C0 = pc * ((P0 & 1u) ? sv0 : cv0);
    float C1 = pc * ((P0 & 1u) ? cv0 : -sv0);
    float cb[6], sb[6];
#pragma unroll
    for (int k = 0; k < 6; ++k) { cb[k] = trig[16 + k]; sb[k] = trig[NQ + 16 + k]; }
    unsigned u0 = P0 >> 16;                                // 6 bits
    float v0[32], v1[32];
#pragma unroll
    for (int e = 0; e < 32; ++e) {
        unsigned F = 0;
        if (e & 1)  F ^= M.frowHi[0];
        if (e & 2)  F ^= M.frowHi[1];
        if (e & 4)  F ^= M.frowHi[2];
        if (e & 8)  F ^= M.frowHi[3];
        if (e & 16) F ^= M.frowHi[4];
        unsigned u = u0 ^ (F >> 16);
        float vp = (u & 1u) ? sb[0] : cb[0];
#pragma unroll
        for (int k = 1; k < 6; ++k) vp *= ((u >> k) & 1u) ? sb[k] : cb[k];
        v0[e] = vp * C0;
        v1[e] = vp * C1;
    }
    float c2[5], s2[5];
#pragma unroll
    for (int j = 0; j < 5; ++j) {
        c2[j] = trig[2 * NQ + 17 + j];
        s2[j] = trig[3 * NQ + 17 + j];
    }
#pragma unroll
    for (int j = 0; j < 5; ++j) {
#pragma unroll
        for (int e = 0; e < 32; ++e) {
            if (!(e & (1 << j))) {
                int e1 = e | (1 << j);
                float a0 = v0[e], a1 = v0[e1];
                v0[e]  = c2[j] * a0 - s2[j] * a1;
                v0[e1] = s2[j] * a0 + c2[j] * a1;
                float b0 = v1[e], b1 = v1[e1];
                v1[e]  = c2[j] * b0 - s2[j] * b1;
                v1[e1] = s2[j] * b0 + c2[j] * b1;
            }
        }
    }
#pragma unroll
    for (int e = 0; e < 32; ++e) {
        unsigned a = base | ((unsigned)e << 17);
        phi[a] = v0[e];
        phi[DIMN + a] = v1[e];
    }
    // measure q1..q3 (x-pairs and z-masks entirely within bits 17..21)
    int lane = threadIdx.x & 63, w = threadIdx.x >> 6;
#pragma unroll
    for (int i = 1; i <= 3; ++i) {
        unsigned ex  = M.xm[i] >> 17;
        unsigned zme = M.zm[i] >> 17;
        float t00 = 0.f, t11 = 0.f, t01 = 0.f, u01 = 0.f;
#pragma unroll
        for (int e = 0; e < 32; ++e) {
            int ep = e ^ (int)ex;
            t00 += v0[e] * v0[ep];
            t11 += v1[e] * v1[ep];
            float p = v0[e] * v1[ep];
            t01 += p;
            unsigned sg = ((unsigned)__popc((unsigned)ep & zme) & 1u) << 31;
            u01 += fflip(p, sg);
        }
        float r = fold4(t00, t11, t01, u01, lane);
        if (lane < 4) red[w * 12 + (i - 1) * 4 + lane] = r;
    }
    __syncthreads();
    int t = threadIdx.x;
    if (t < 12) {
        float r = red[t] + red[12 + t] + red[24 + t] + red[36 + t];
        atomicAdd(&acc[4 + t], r);                          // acc[4..15] = q1..q3
    }
}

// ---- e=bits12..16 tile: gates 12..16 + measure q5..q8 ----
__global__ __launch_bounds__(256, 1) void k_midA(float* __restrict__ phi,
                                                 const float* __restrict__ trig,
                                                 float* __restrict__ acc) {
    constexpr MaskSet M = buildMasks();
    __shared__ float red[4 * 16];
    unsigned tid = blockIdx.x * 256u + threadIdx.x;        // [0, 2^17)
    unsigned base = (tid & 0xFFFu) | ((tid >> 12) << 17);  // bits 0..11 + 17..21
    float v0[32], v1[32];
#pragma unroll
    for (int e = 0; e < 32; ++e) {
        unsigned a = base | ((unsigned)e << 12);
        v0[e] = phi[a];
        v1[e] = phi[DIMN + a];
    }
    float c[5], s[5];
#pragma unroll
    for (int j = 0; j < 5; ++j) {
        c[j] = trig[2 * NQ + 12 + j];
        s[j] = trig[3 * NQ + 12 + j];
    }
#pragma unroll
    for (int j = 0; j < 5; ++j) {
#pragma unroll
        for (int e = 0; e < 32; ++e) {
            if (!(e & (1 << j))) {
                int e1 = e | (1 << j);
                float a0 = v0[e], a1 = v0[e1];
                v0[e]  = c[j] * a0 - s[j] * a1;
                v0[e1] = s[j] * a0 + c[j] * a1;
                float b0 = v1[e], b1 = v1[e1];
                v1[e]  = c[j] * b0 - s[j] * b1;
                v1[e1] = s[j] * b0 + c[j] * b1;
            }
        }
    }
#pragma unroll
    for (int e = 0; e < 32; ++e) {
        unsigned a = base | ((unsigned)e << 12);
        phi[a] = v0[e];
        phi[DIMN + a] = v1[e];
    }
    // measure q5..q8 (x-pairs within bits 12..16; z-masks suffix >= 13)
    int lane = threadIdx.x & 63, w = threadIdx.x >> 6;
#pragma unroll
    for (int i = 5; i <= 8; ++i) {
        unsigned ex  = (M.xm[i] >> 12) & 31u;
        unsigned zme = (M.zm[i] >> 12) & 31u;
        unsigned bs31 = ((unsigned)__popc(base & M.zm[i]) & 1u) << 31;
        float t00 = 0.f, t11 = 0.f, t01 = 0.f, u01 = 0.f;
#pragma unroll
        for (int e = 0; e < 32; ++e) {
            int ep = e ^ (int)ex;
            t00 += v0[e] * v0[ep];
            t11 += v1[e] * v1[ep];
            float p = v0[e] * v1[ep];
            t01 += p;
            unsigned sg = ((unsigned)__popc((unsigned)ep & zme) & 1u) << 31;
            u01 += fflip(p, sg ^ bs31);
        }
        float r = fold4(t00, t11, t01, u01, lane);
        if (lane < 4) red[w * 16 + (i - 5) * 4 + lane] = r;
    }
    __syncthreads();
    int t = threadIdx.x;
    if (t < 16) {
        float r = red[t] + red[16 + t] + red[32 + t] + red[48 + t];
        atomicAdd(&acc[20 + t], r);                         // acc[20..35] = q5..q8
    }
}

// ---- RY layer 2 bits 0..11 + q10..q20 X/Y + ALL Z measurements ----
// 512 threads, 8 elems/thread, 4 exchange phases -> 32 waves/CU (LDS 35 KB, 4 blk/CU)
__global__ __launch_bounds__(512, 8) void k_low(float* __restrict__ phi,
                                                const float* __restrict__ trig,
                                                float* __restrict__ acc) {
    constexpr MaskSet M = buildMasks();
    __shared__ float As[4096];
    __shared__ float Bs[4096];
    __shared__ float redZ[8 * 33];
    __shared__ float redQ[8 * 44];
    float4* As4 = (float4*)As;
    float4* Bs4 = (float4*)Bs;
    int t = threadIdx.x;
    int lane = t & 63, w = t >> 6;
    unsigned base = blockIdx.x * 4096u;
    float a[8], b[8];

    // ---- P0: load (8 consecutive elems/thread), gates bits 0..2, store ----
    {
        const float4* g0 = (const float4*)(phi + base);
        const float4* g1 = (const float4*)(phi + DIMN + base);
#pragma unroll
        for (int k = 0; k < 2; ++k) {
            float4 va = g0[2 * t + k];
            a[4 * k] = va.x; a[4 * k + 1] = va.y; a[4 * k + 2] = va.z; a[4 * k + 3] = va.w;
            float4 vb = g1[2 * t + k];
            b[4 * k] = vb.x; b[4 * k + 1] = vb.y; b[4 * k + 2] = vb.z; b[4 * k + 3] = vb.w;
        }
        gates3(a, b, trig, 0);
#pragma unroll
        for (int j = 0; j < 8; ++j) {
            unsigned i = ((unsigned)t << 3) | (unsigned)j;
            unsigned A = sA(i);
            As[A] = a[j]; Bs[A] = b[j];
        }
    }
    __syncthreads();

    // ---- X01 read (j = bits 3..5), gates 3..5, write back same addresses ----
    {
#pragma unroll
        for (int j = 0; j < 8; ++j) {
            unsigned i = (((unsigned)t >> 3) << 6) | ((unsigned)j << 3) | ((unsigned)t & 7u);
            unsigned A = sA(i);
            a[j] = As[A]; b[j] = Bs[A];
        }
        gates3(a, b, trig, 3);
#pragma unroll
        for (int j = 0; j < 8; ++j) {
            unsigned i = (((unsigned)t >> 3) << 6) | ((unsigned)j << 3) | ((unsigned)t & 7u);
            unsigned A = sA(i);
            As[A] = a[j]; Bs[A] = b[j];
        }
    }
    __syncthreads();

    // ---- X12 read (j = bits 6..8), gates 6..8, write back ----
    {
#pragma unroll
        for (int j = 0; j < 8; ++j) {
            unsigned i = (((unsigned)t >> 6) << 9) | ((unsigned)j << 6) | ((unsigned)t & 63u);
            unsigned A = sA(i);
            a[j] = As[A]; b[j] = Bs[A];
        }
        gates3(a, b, trig, 6);
#pragma unroll
        for (int j = 0; j < 8; ++j) {
            unsigned i = (((unsigned)t >> 6) << 9) | ((unsigned)j << 6) | ((unsigned)t & 63u);
            unsigned A = sA(i);
            As[A] = a[j]; Bs[A] = b[j];
        }
    }
    __syncthreads();

    // ---- X23 read (j = bits 9..11), gates 9..11 ----
    {
#pragma unroll
        for (int j = 0; j < 8; ++j) {
            unsigned i = ((unsigned)j << 9) | (unsigned)t;
            unsigned A = sA(i);
            a[j] = As[A]; b[j] = Bs[A];
        }
        gates3(a, b, trig, 9);
    }
    __syncthreads();   // protect As/Bs before measurement-layout overwrite

    // ---- write phi + measurement-layout LDS (elem i at i ^ (((i>>8)&3)<<2)) ----
#pragma unroll
    for (int j = 0; j < 8; ++j) {
        unsigned i = ((unsigned)j << 9) | (unsigned)t;
        phi[base + i] = a[j];
        phi[DIMN + base + i] = b[j];
        unsigned p = i ^ (((i >> 8) & 3u) << 2);
        As[p] = a[j]; Bs[p] = b[j];
    }

    // ---- fused Z measurement from regs: 3-level tree (bits 9..11) + lane Walsh ----
#pragma unroll
    for (int c = 0; c < 3; ++c) {
        float p[8];
#pragma unroll
        for (int j = 0; j < 8; ++j)
            p[j] = (c == 0) ? a[j] * a[j] : (c == 1) ? b[j] * b[j] : a[j] * b[j];
        float s1[4], d1[4];
#pragma unroll
        for (int j = 0; j < 4; ++j) { s1[j] = p[j] + p[j + 4]; d1[j] = p[j] - p[j + 4]; }
        float s2_0 = s1[0] + s1[2], s2_1 = s1[1] + s1[3];
        float d2_0 = d1[0] - d1[2], d2_1 = d1[1] - d1[3];
        float SS = s2_0 + s2_1;
        float z0 = (d1[0] + d1[1]) + (d1[2] + d1[3]);     // sign: bit 11
        float z1 = d2_0 + d2_1;                           // sign: bits 11,10
        float d3 = d2_0 - d2_1;                           // sign: bits 11,10,9
        float r = fold4(SS, z0, z1, 0.f, lane);
        if (lane < 3) redZ[w * 33 + c * 11 + lane] = r;
        float v = d3;
#pragma unroll
        for (int s = 0; s < 6; ++s) {
            float u = __shfl_xor(v, 1 << s);
            v = u + fflip(v, ((unsigned)(lane >> s) & 1u) << 31);
        }
        int pcnt = __popc(lane);
        if (lane == 64 - (64 >> pcnt)) redZ[w * 33 + c * 11 + 3 + pcnt] = v;
    }
    __syncthreads();   // redZ + measurement-layout As/Bs visible

    // ---- Z combine over 8 waves with wave-bit signs (elem bits 6..8) ----
    if (t < 66) {
        int c = t % 3, q = t / 3;
        int idx, wm;
        if (q == 0 || q == 21)      { idx = 9; wm = 7; }   // full suffix
        else if (q <= 9)            { idx = 0; wm = 0; }   // SS (suffix above tile)
        else if (q == 10)           { idx = 1; wm = 0; }
        else if (q == 11)           { idx = 2; wm = 0; }
        else if (q == 12)           { idx = 3; wm = 0; }
        else if (q == 13)           { idx = 3; wm = 4; }
        else if (q == 14)           { idx = 3; wm = 6; }
        else if (q == 15)           { idx = 3; wm = 7; }
        else                        { idx = q - 12; wm = 7; }  // q16..q20 -> 4..8
        float val = 0.f;
#pragma unroll
        for (int ww = 0; ww < 8; ++ww) {
            float rv = redZ[ww * 33 + c * 11 + idx];
            val += ((__popc(ww & wm) & 1) ? -rv : rv);
        }
        unsigned sg = (unsigned)__popc(base & M.zm[q]) & 1u;
        atomicAdd(&acc[4 * NQ + 3 * q + c], sg ? -val : val);
    }

    // ---- q10,q11 from registers (x-pairs within bits 9..11 = j bits) ----
#pragma unroll
    for (int i = 0; i < 2; ++i) {
        int q = 10 + i;
        unsigned je  = (M.xm[q] >> 9) & 7u;
        unsigned zmj = (M.zm[q] >> 9) & 7u;
        unsigned zb31 = ((unsigned)__popc(base & M.zm[q]) & 1u) << 31;
        float t00 = 0.f, t11 = 0.f, t01 = 0.f, u01 = 0.f;
#pragma unroll
        for (int j = 0; j < 8; ++j) {
            int jp = j ^ (int)je;
            t00 += a[j] * a[jp];
            t11 += b[j] * b[jp];
            float p = a[j] * b[jp];
            t01 += p;
            unsigned sg = ((unsigned)__popc((unsigned)jp & zmj) & 1u) << 31;
            u01 += fflip(p, sg ^ zb31);
        }
        float r = fold4(t00, t11, t01, u01, lane);
        if (lane < 4) redQ[w * 44 + 4 * i + lane] = r;
    }

    // ---- q12..q19 (generic float4-pair path), q20 special ----
#pragma unroll
    for (int iq = 2; iq < 10; ++iq) {
        int q = 10 + iq;
        unsigned m = M.xm[q], zm = M.zm[q];
        unsigned zb = (unsigned)__popc(base & zm) & 1u;
        int gb = topbit_c(M.xm[q]) - 2;
        unsigned mg4 = m >> 2;
        unsigned swap2 = m & 3u;            // 0 or 2
        float t00 = 0.f, t11 = 0.f, t01 = 0.f, u01 = 0.f;
        unsigned gc = (unsigned)t;          // 0..511: covers all 512 half-pairs
        unsigned g = ((gc >> gb) << (gb + 1)) | (gc & ((1u << gb) - 1u));
        unsigned gx = g ^ mg4;
        float4 a0 = As4[ph4(g)],  a1 = Bs4[ph4(g)];
        float4 b0 = As4[ph4(gx)], b1 = Bs4[ph4(gx)];
        if (swap2) {
            b0 = make_float4(b0.z, b0.w, b0.x, b0.y);
            b1 = make_float4(b1.z, b1.w, b1.x, b1.y);
        }
        unsigned szg = ((unsigned)__popc((g << 2) & zm) + zb) & 1u;
        unsigned szx = ((unsigned)__popc((gx << 2) & zm) + zb) & 1u;
        unsigned fg = szg << 31, fx = szx << 31;
        const float* A0 = &a0.x; const float* A1 = &a1.x;
        const float* B0 = &b0.x; const float* B1 = &b1.x;
#pragma unroll
        for (int j = 0; j < 4; ++j) {
            t00 += A0[j] * B0[j];
            t11 += A1[j] * B1[j];
            float p = A0[j] * B1[j], r2 = B0[j] * A1[j];
            t01 += p + r2;
            u01 += fflip(p, fx) + fflip(r2, fg);
        }
        t00 *= 2.f; t11 *= 2.f;
        float r = fold4(t00, t11, t01, u01, lane);
        if (lane < 4) redQ[w * 44 + 4 * iq + lane] = r;
    }
    {
        // q20: m = 3, partner within float4; zm&3 == 2
        unsigned zm = M.zm[20];
        unsigned zb = (unsigned)__popc(base & zm) & 1u;
        float t00 = 0.f, t11 = 0.f, t01 = 0.f, u01 = 0.f;
#pragma unroll
        for (int k = 0; k < 2; ++k) {
            unsigned g = (unsigned)t + 512u * k;
            float4 a0 = As4[ph4(g)], a1 = Bs4[ph4(g)];
            unsigned szg = ((unsigned)__popc((g << 2) & zm) + zb) & 1u;
            const float* A0 = &a0.x; const float* A1 = &a1.x;
#pragma unroll
            for (int j = 0; j < 4; ++j) {
                int jx = j ^ 3;
                float p = A0[j] * A0[jx];
                float q2 = A1[j] * A1[jx];
                float cr = A0[j] * A1[jx];
                t00 += p; t11 += q2; t01 += cr;
                unsigned sj = ((unsigned)(jx >> 1) & 1u) ^ szg;   // zm&3 == 2
                u01 += fflip(cr, sj << 31);
            }
        }
        float r = fold4(t00, t11, t01, u01, lane);
        if (lane < 4) redQ[w * 44 + 40 + lane] = r;
    }
    __syncthreads();
    if (t < 44) {
        float r = 0.f;
#pragma unroll
        for (int ww = 0; ww < 8; ++ww) r += redQ[ww * 44 + t];
        atomicAdd(&acc[40 + t], r);
    }
}

// ------- fused single-pass X/Y measurements for q0, q4, q9, q21 --------------
__global__ __launch_bounds__(256) void k_measF(const float* __restrict__ phi,
                                               float* __restrict__ acc) {
    constexpr MaskSet M = buildMasks();
    constexpr unsigned GA = orbGen(0), GB = orbGen(1), GC = orbGen(2);
    constexpr int pc0 = topbit_c(GC), pc1 = topbit_c(GB), pc2 = topbit_c(GA);
    __shared__ float red[4 * 16];
    unsigned t = blockIdx.x * 256u + threadIdx.x;          // 17-bit orbit id
    unsigned g = t;                                        // insert 0 at canonical bits
    g = ((g >> pc0) << (pc0 + 1)) | (g & ((1u << pc0) - 1u));
    g = ((g >> pc1) << (pc1 + 1)) | (g & ((1u << pc1) - 1u));
    g = ((g >> pc2) << (pc2 + 1)) | (g & ((1u << pc2) - 1u));
    const float4* P0 = (const float4*)phi;
    const float4* P1 = (const float4*)(phi + DIMN);
    unsigned idx[8];
    float4 u4[8], w4[8];
#pragma unroll
    for (int s = 0; s < 8; ++s) {
        idx[s] = g ^ ((s & 1) ? GA : 0u) ^ ((s & 2) ? GB : 0u) ^ ((s & 4) ? GC : 0u);
        u4[s] = P0[idx[s]];
        w4[s] = P1[idx[s]];
    }
    constexpr int QN[4] = { 0, 4, 9, 21 };
    constexpr int SX[4] = { 1, 2, 4, orbS21() };
    float res[16];
#pragma unroll
    for (int qi = 0; qi < 4; ++qi) {
        const unsigned xq = M.xm[QN[qi]];
        const unsigned zq = M.zm[QN[qi]];
        const int sx = SX[qi];
        const int mu = (int)(xq & 3u);                     // within-f4 partner xor
        const unsigned zh = zq >> 2, zl = zq & 3u;
        unsigned fz[8];
#pragma unroll
        for (int s = 0; s < 8; ++s)
            fz[s] = ((unsigned)__popc(idx[s] & zh) & 1u) << 31;
        unsigned pj31[4];
#pragma unroll
        for (int j = 0; j < 4; ++j)
            pj31[j] = ((unsigned)__popc((unsigned)j & zl) & 1u) << 31;
        float t00 = 0.f, t11 = 0.f, t01 = 0.f, u01 = 0.f;
#pragma unroll
        for (int s = 0; s < 8; ++s) {
            const int s2 = s ^ sx;
            const float* A0 = &u4[s].x;
            const float* A1 = &w4[s].x;
            const float* B0 = &u4[s2].x;
            const float* B1 = &w4[s2].x;
            const unsigned fe = fz[s2];                    // Z-parity of partner f4
#pragma unroll
            for (int j = 0; j < 4; ++j) {
                const int jp = j ^ mu;
                t00 += A0[j] * B0[jp];
                t11 += A1[j] * B1[jp];
                float p = A0[j] * B1[jp];
                t01 += p;
                u01 += fflip(p, fe ^ pj31[jp]);
            }
        }
        res[4 * qi + 0] = t00; res[4 * qi + 1] = t11;
        res[4 * qi + 2] = t01; res[4 * qi + 3] = u01;
    }
    int lane = threadIdx.x & 63, w = threadIdx.x >> 6;
#pragma unroll
    for (int g4 = 0; g4 < 4; ++g4) {
        float r = fold4(res[4 * g4 + 0], res[4 * g4 + 1], res[4 * g4 + 2], res[4 * g4 + 3], lane);
        if (lane < 4) red[w * 16 + 4 * g4 + lane] = r;
    }
    __syncthreads();
    int tt = threadIdx.x;
    if (tt < 16) {
        int qi = tt >> 2;
        int base4 = (qi == 0) ? 0 : (qi == 1) ? 16 : (qi == 2) ? 36 : 84;  // 4*qn
        float r = red[tt] + red[16 + tt] + red[32 + tt] + red[48 + tt];
        atomicAdd(&acc[base4 + (tt & 3)], r);
    }
}

// ---------------- finalize: combine 154 sums into the scalar loss ----------------
__global__ __launch_bounds__(64) void k_final(const float* __restrict__ acc,
                                              float* __restrict__ out) {
    int t = threadIdx.x;
    float v = 0.f;
    if (t < NQ) {
        float t00 = acc[4 * t], t11 = acc[4 * t + 1];
        float t01 = acc[4 * t + 2], u01 = acc[4 * t + 3];
        float d = t00 - t11;
        v = 0.5f * d * d + 2.f * t01 * t01 + 2.f * u01 * u01;   // X op + Y op
    } else if (t < 2 * NQ) {
        int q = t - NQ;
        float z0 = acc[4 * NQ + 3 * q], z1 = acc[4 * NQ + 3 * q + 1];
        float zz = acc[4 * NQ + 3 * q + 2];
        float d = z0 - z1;
        v = 0.5f * d * d + 2.f * zz * zz;                       // Z op
    }
    v += __shfl_down(v, 32); v += __shfl_down(v, 16); v += __shfl_down(v, 8);
    v += __shfl_down(v, 4);  v += __shfl_down(v, 2);  v += __shfl_down(v, 1);
    if (t == 0) out[0] = v;
}

extern "C" void kernel_launch(void* const* d_in, const int* in_sizes, int n_in,
                              void* d_out, int out_size, void* d_ws, size_t ws_size,
                              hipStream_t stream) {
    const float* theta = (const float*)d_in[0];
    float* out  = (float*)d_out;
    float* ws   = (float*)d_ws;
    float* phi  = ws;                          // 2 * DIMN floats (32 MB)
    float* acc  = ws + 2 * (size_t)DIMN;       // 256 floats
    float* trig = acc + 256;                   // 88 floats

    k_prep<<<1, 256, 0, stream>>>(theta, acc, trig);
    k_genHi<<<512, 256, 0, stream>>>(phi, trig, acc);
    k_midA<<<512, 256, 0, stream>>>(phi, trig, acc);
    k_low<<<1024, 512, 0, stream>>>(phi, trig, acc);
    k_measF<<<512, 256, 0, stream>>>(phi, acc);
    k_final<<<1, 64, 0, stream>>>(acc, out);
}